// Round 10
// baseline (152.463 us; speedup 1.0000x reference)
//
#include <hip/hip_runtime.h>

// SOM BMU: argmin_m (w_sq[m] - 2*dot(x,w[m])) -> (idx/128, idx%128).
// Single-pass filter + exact rescore:
//   hh (f16-hi) MFMA GEMM; per coltile: running per-row min + collect
//   (key,col) for cols within MARGIN of the running min (~10-20/row).
//   Rescore: prune by list-global hh-min + MARGIN (~1-3 survive), exact
//   fp32 wave-dot rescore, decode.
// |hh - true| <= ~0.5 worst case << MARGIN=1.5 (certified cover):
//   hh(c*) <= true(c*)+0.5 <= true(c_hh)+0.5 <= hh(c_hh)+1.0 <= runmin+1.0.
// GEMM shape (measured-good, round 9): 128x128 coltile, 4 waves, BK=64,
// 64KB dbuf LDS, acc[4][4] -> ~88 arch VGPR, 2 blocks/CU.

#define B_ROWS 4096
#define M_COLS 16384
#define KF 256
#define BM 128
#define NCHUNK 16
#define NSTEP 32          // 8 coltiles * 4 k-steps (BK=64)
#define CAP 128
#define MARGIN 1.5f

typedef _Float16 f16x8 __attribute__((ext_vector_type(8)));
typedef float f32x4 __attribute__((ext_vector_type(4)));
typedef unsigned long long u64;

#define GLOAD16(gsrc, ldst) \
  __builtin_amdgcn_global_load_lds((const __attribute__((address_space(1))) void*)(gsrc), \
                                   (__attribute__((address_space(3))) void*)(ldst), 16, 0, 0)

// tile-major: tiles of 128 rows; per (tile,ks32): [kch=4][r=128][8] halves = 8KB
__device__ __forceinline__ size_t tm_idx(int tile, int ks, int kch, int r) {
    return ((((size_t)(tile * 8 + ks)) * 4 + kch) * 128 + r) * 8;
}

__device__ __forceinline__ unsigned fkey(float s) {
    const unsigned fb = __float_as_uint(s);
    return (fb & 0x80000000u) ? ~fb : (fb | 0x80000000u);
}
__device__ __forceinline__ float unkey(unsigned k) {
    return (k & 0x80000000u) ? __uint_as_float(k & 0x7fffffffu) : __uint_as_float(~k);
}

// ---------------- kernel 1: split X -> tile-major f16 hi; init cnt ----------------
__global__ __launch_bounds__(256) void som_split_x(const float* __restrict__ xb,
                                                   _Float16* __restrict__ xh,
                                                   unsigned* __restrict__ cnt) {
    const int gid = blockIdx.x * 256 + threadIdx.x;
    if (gid < B_ROWS) cnt[gid] = 0u;
    const int row = gid >> 5;
    const int kg = gid & 31;
    const float4 v0 = *reinterpret_cast<const float4*>(xb + (size_t)row * KF + kg * 8);
    const float4 v1 = *reinterpret_cast<const float4*>(xb + (size_t)row * KF + kg * 8 + 4);
    const float vv[8] = {v0.x, v0.y, v0.z, v0.w, v1.x, v1.y, v1.z, v1.w};
    f16x8 h;
#pragma unroll
    for (int j = 0; j < 8; ++j) h[j] = (_Float16)vv[j];
    *reinterpret_cast<f16x8*>(xh + tm_idx(row >> 7, kg >> 2, kg & 3, row & 127)) = h;
}

// ---------------- kernel 2: split W -> tile-major f16 hi + w_sq ----------------
__global__ __launch_bounds__(256) void som_split_w(const float* __restrict__ wt,
                                                   _Float16* __restrict__ wh,
                                                   float* __restrict__ wsq) {
    const int gid = blockIdx.x * 256 + threadIdx.x;
    const int row = gid >> 5;
    const int kg = gid & 31;
    const float4 v0 = *reinterpret_cast<const float4*>(wt + (size_t)row * KF + kg * 8);
    const float4 v1 = *reinterpret_cast<const float4*>(wt + (size_t)row * KF + kg * 8 + 4);
    const float vv[8] = {v0.x, v0.y, v0.z, v0.w, v1.x, v1.y, v1.z, v1.w};
    f16x8 h;
    float s = 0.0f;
#pragma unroll
    for (int j = 0; j < 8; ++j) {
        h[j] = (_Float16)vv[j];
        s += vv[j] * vv[j];
    }
    *reinterpret_cast<f16x8*>(wh + tm_idx(row >> 7, kg >> 2, kg & 3, row & 127)) = h;
#pragma unroll
    for (int off = 16; off > 0; off >>= 1) s += __shfl_down(s, off, 64);
    if (kg == 0) wsq[row] = s;   // lanes 0 and 32 each own a row
}

// ---------------- kernel 3: hh GEMM + fused running-min collect ----------------
__global__ __launch_bounds__(256, 2) void som_main(const _Float16* __restrict__ xh,
                                                   const _Float16* __restrict__ wh,
                                                   const float* __restrict__ wsq,
                                                   unsigned* __restrict__ cnt,
                                                   u64* __restrict__ list) {
    __shared__ _Float16 lds[2][2][8192];   // [buf][A,B][kk=2][kch=4][r=128][8], 64 KB

    const int tid = threadIdx.x;
    const int lane = tid & 63;
    const int frow = lane & 15;
    const int kch = lane >> 4;
    const int wid = tid >> 6;
    const int wr = wid >> 1;      // wave row (0..1): 64 rows
    const int wc = wid & 1;       // wave col (0..1): 64 cols

    // bijective XCD swizzle (512 blocks, 512%8==0)
    const int id = blockIdx.x;
    const int swz = (id & 7) * 64 + (id >> 3);
    const int bx = swz & 31;      // row tile (0..31)
    const int by = swz >> 5;      // col chunk (0..15)
    const int rowbase = bx * BM;

    const int ebase = (tid & 192) * 8;   // wave-uniform LDS base (halves)
    const int tid8 = tid * 8;

    float rowbest[16];
#pragma unroll
    for (int i = 0; i < 16; ++i) rowbest[i] = 3.4e38f;

    f32x4 acc[4][4];

#define STAGE(buf_, step_) do {                                               \
    const int ct_ = (step_) >> 2, t_ = (step_) & 3;                           \
    const size_t ab_ = (size_t)(bx * 8 + 2 * t_) * 4096;                      \
    const size_t bb_ = (size_t)((by * 8 + ct_) * 8 + 2 * t_) * 4096;          \
    GLOAD16(xh + ab_ + tid8,        &lds[buf_][0][ebase]);                    \
    GLOAD16(xh + ab_ + 2048 + tid8, &lds[buf_][0][2048 + ebase]);             \
    GLOAD16(xh + ab_ + 4096 + tid8, &lds[buf_][0][4096 + ebase]);             \
    GLOAD16(xh + ab_ + 6144 + tid8, &lds[buf_][0][6144 + ebase]);             \
    GLOAD16(wh + bb_ + tid8,        &lds[buf_][1][ebase]);                    \
    GLOAD16(wh + bb_ + 2048 + tid8, &lds[buf_][1][2048 + ebase]);             \
    GLOAD16(wh + bb_ + 4096 + tid8, &lds[buf_][1][4096 + ebase]);             \
    GLOAD16(wh + bb_ + 6144 + tid8, &lds[buf_][1][6144 + ebase]);             \
  } while (0)

    STAGE(0, 0);
    int buf = 0;

    for (int step = 0; step < NSTEP; ++step) {
        __syncthreads();   // stage(step) landed; everyone done reading buf^1
        if (step < NSTEP - 1) STAGE(buf ^ 1, step + 1);

        if ((step & 3) == 0) {
#pragma unroll
            for (int m = 0; m < 4; ++m)
#pragma unroll
                for (int n = 0; n < 4; ++n) acc[m][n] = (f32x4){0.f, 0.f, 0.f, 0.f};
        }

#pragma unroll
        for (int kk = 0; kk < 2; ++kk) {
            f16x8 bh[4];
#pragma unroll
            for (int n = 0; n < 4; ++n)
                bh[n] = *reinterpret_cast<const f16x8*>(
                    &lds[buf][1][kk * 4096 + kch * 1024 + (wc * 64 + n * 16 + frow) * 8]);
#pragma unroll
            for (int m = 0; m < 4; ++m) {
                const f16x8 ah = *reinterpret_cast<const f16x8*>(
                    &lds[buf][0][kk * 4096 + kch * 1024 + (wr * 64 + m * 16 + frow) * 8]);
#pragma unroll
                for (int n = 0; n < 4; ++n)
                    acc[m][n] = __builtin_amdgcn_mfma_f32_16x16x32_f16(ah, bh[n], acc[m][n], 0, 0, 0);
            }
        }

        if ((step & 3) == 3) {
            // coltile epilogue: scores, running row-min, margin-collect.
            // C/D layout: col=lane&15, row=(lane>>4)*4+reg
            const int ct = step >> 2;
            const int cb = by * 1024 + ct * 128 + wc * 64 + frow;
            float wq[4];
#pragma unroll
            for (int n = 0; n < 4; ++n) wq[n] = wsq[cb + n * 16];
#pragma unroll
            for (int i = 0; i < 16; ++i) {
                const int m = i >> 2, r = i & 3;
                float s[4];
#pragma unroll
                for (int n = 0; n < 4; ++n) s[n] = wq[n] - 2.0f * acc[m][n][r];
                float sm = fminf(fminf(s[0], s[1]), fminf(s[2], s[3]));
#pragma unroll
                for (int mk = 1; mk <= 8; mk <<= 1)
                    sm = fminf(sm, __shfl_xor(sm, mk, 64));
                rowbest[i] = fminf(rowbest[i], sm);
                const float thr = rowbest[i] + MARGIN;
                const int rowg = rowbase + wr * 64 + m * 16 + kch * 4 + r;
#pragma unroll
                for (int n = 0; n < 4; ++n) {
                    if (s[n] <= thr) {
                        const unsigned slot = atomicAdd(&cnt[rowg], 1u);
                        if (slot < CAP)
                            list[(size_t)rowg * CAP + slot] =
                                ((u64)fkey(s[n]) << 32) | (unsigned)(cb + n * 16);
                    }
                }
            }
        }
        buf ^= 1;
    }
#undef STAGE
}

// ---------------- kernel 4: prune + exact fp32 rescore + decode ----------------
__global__ __launch_bounds__(256) void som_rescore(const float* __restrict__ xb,
                                                   const float* __restrict__ wt,
                                                   const float* __restrict__ wsq,
                                                   const u64* __restrict__ list,
                                                   const unsigned* __restrict__ cnt,
                                                   int* __restrict__ out) {
    const int row = (blockIdx.x * 256 + threadIdx.x) >> 6;   // one wave per row
    const int lane = threadIdx.x & 63;
    if (row >= B_ROWS) return;
    const float4 xv = *reinterpret_cast<const float4*>(xb + (size_t)row * KF + lane * 4);
    const unsigned n = cnt[row];
    u64 best = ~0ull;
    if (n <= CAP) {
        // global hh-min key over the list
        u64 kmin = ~0ull;
        for (unsigned i = lane; i < n; i += 64) {
            const u64 p = list[(size_t)row * CAP + i];
            if (p < kmin) kmin = p;
        }
#pragma unroll
        for (int mk = 1; mk <= 32; mk <<= 1) {
            const u64 o = __shfl_xor(kmin, mk, 64);
            if (o < kmin) kmin = o;
        }
        const float thr = unkey((unsigned)(kmin >> 32)) + MARGIN;
        // lane-parallel prune, ballot survivors, wave-dot each survivor
        for (unsigned base = 0; base < n; base += 64) {
            const unsigned i = base + lane;
            u64 p = ~0ull;
            bool keep = false;
            if (i < n) {
                p = list[(size_t)row * CAP + i];
                keep = unkey((unsigned)(p >> 32)) <= thr;
            }
            unsigned long long mask = __ballot(keep);
            while (mask) {
                const int src = __ffsll((unsigned long long)mask) - 1;
                mask &= mask - 1;
                const int col = (int)(__shfl(p, src, 64) & 0xffffffffu);
                const float4 wv = *reinterpret_cast<const float4*>(wt + (size_t)col * KF + lane * 4);
                float d = xv.x * wv.x + xv.y * wv.y + xv.z * wv.z + xv.w * wv.w;
#pragma unroll
                for (int mk = 1; mk <= 32; mk <<= 1) d += __shfl_xor(d, mk, 64);
                const float sc = wsq[col] - 2.0f * d;
                const u64 q = ((u64)fkey(sc) << 32) | (unsigned)col;
                if (q < best) best = q;
            }
        }
    } else {
        // overflow fallback (never-path, deterministic): exact scan of all cols
        for (int col = 0; col < M_COLS; ++col) {
            const float4 wv = *reinterpret_cast<const float4*>(wt + (size_t)col * KF + lane * 4);
            float d = xv.x * wv.x + xv.y * wv.y + xv.z * wv.z + xv.w * wv.w;
#pragma unroll
            for (int mk = 1; mk <= 32; mk <<= 1) d += __shfl_xor(d, mk, 64);
            const float sc = wsq[col] - 2.0f * d;
            const u64 q = ((u64)fkey(sc) << 32) | (unsigned)col;
            if (q < best) best = q;
        }
    }
    if (lane == 0) {
        const int idx = (int)(best & 0xffffffffu);
        out[2 * row] = idx >> 7;      // idx / 128
        out[2 * row + 1] = idx & 127; // idx % 128
    }
}

extern "C" void kernel_launch(void* const* d_in, const int* in_sizes, int n_in,
                              void* d_out, int out_size, void* d_ws, size_t ws_size,
                              hipStream_t stream) {
    const float* xb = (const float*)d_in[0];   // [4096, 256] fp32
    const float* wt = (const float*)d_in[1];   // [16384, 256] fp32
    int* out = (int*)d_out;                    // [4096, 2] int32

    char* ws = (char*)d_ws;
    _Float16* xh  = (_Float16*)(ws);                                   // 2 MB
    _Float16* wh  = (_Float16*)(ws + (size_t)2 * 1024 * 1024);         // 8 MB
    float*    wsq = (float*)(ws + (size_t)10 * 1024 * 1024);           // 64 KB
    unsigned* cnt = (unsigned*)(ws + (size_t)10 * 1024 * 1024 + 65536);    // 16 KB
    u64*     list = (u64*)(ws + (size_t)10 * 1024 * 1024 + 131072);        // 4 MB

    som_split_x<<<(B_ROWS * 32) / 256, 256, 0, stream>>>(xb, xh, cnt);
    som_split_w<<<(M_COLS * 32) / 256, 256, 0, stream>>>(wt, wh, wsq);
    som_main<<<BM * NCHUNK / 4, 256, 0, stream>>>(xh, wh, wsq, cnt, list);
    som_rescore<<<B_ROWS / 4, 256, 0, stream>>>(xb, wt, wsq, list, cnt, out);
}